// Round 1
// baseline (1706.653 us; speedup 1.0000x reference)
//
#include <hip/hip_runtime.h>
#include <hip/hip_bf16.h>
#include <float.h>

#define NN 4000      // nodes
#define NE 20000     // edges
#define DD 512       // D
#define NT 4         // towers
#define FO 128       // F_OUT
#define TD 2048      // NT*DD (also 4*DD chunk stride in A)
#define AD 8192      // NT*4*DD per-node A row
#define NG 32
#define NC 10
#define AVGLOG 1.2548916493836102f
#define EPS_STD_ 1e-5f
#define EPS_BN_ 1e-5f

// ---------------- generic 64x64 fp32 GEMM core (BK=16, 256 thr, 4x4/thread) ----------------
__device__ __forceinline__ void gemm_core(
    const float* __restrict__ A, int lda,
    const float* __restrict__ B, int ldb,
    float* __restrict__ C, int ldc,
    int M, int K, const float* __restrict__ bias)
{
    __shared__ float As[16][64];
    __shared__ float Bs[16][64];
    const int tid = threadIdx.x;
    const int tx = tid & 15, ty = tid >> 4;
    const int m0 = blockIdx.y * 64, n0 = blockIdx.x * 64;
    float acc[4][4];
#pragma unroll
    for (int i = 0; i < 4; ++i)
#pragma unroll
        for (int j = 0; j < 4; ++j) acc[i][j] = 0.f;

    const int lm = tid >> 2;          // 0..63  A row within tile
    const int lk = (tid & 3) << 2;    // 0,4,8,12
    const int bk = tid >> 4;          // 0..15  B row within tile
    const int bc = (tid & 15) << 2;   // 0..60

    for (int k0 = 0; k0 < K; k0 += 16) {
        float4 av = make_float4(0.f, 0.f, 0.f, 0.f);
        const int row = m0 + lm;
        if (row < M) av = *(const float4*)(A + (size_t)row * lda + k0 + lk);
        As[lk + 0][lm] = av.x; As[lk + 1][lm] = av.y;
        As[lk + 2][lm] = av.z; As[lk + 3][lm] = av.w;
        *(float4*)(&Bs[bk][bc]) = *(const float4*)(B + (size_t)(k0 + bk) * ldb + n0 + bc);
        __syncthreads();
#pragma unroll
        for (int kk = 0; kk < 16; ++kk) {
            float a[4], b[4];
#pragma unroll
            for (int i = 0; i < 4; ++i) a[i] = As[kk][(ty << 2) + i];
#pragma unroll
            for (int j = 0; j < 4; ++j) b[j] = Bs[kk][(tx << 2) + j];
#pragma unroll
            for (int i = 0; i < 4; ++i)
#pragma unroll
                for (int j = 0; j < 4; ++j) acc[i][j] += a[i] * b[j];
        }
        __syncthreads();
    }
    float bb[4] = {0.f, 0.f, 0.f, 0.f};
    if (bias) {
#pragma unroll
        for (int j = 0; j < 4; ++j) bb[j] = bias[n0 + (tx << 2) + j];
    }
#pragma unroll
    for (int i = 0; i < 4; ++i) {
        const int row = m0 + (ty << 2) + i;
        if (row < M) {
            float4 o;
            o.x = acc[i][0] + bb[0]; o.y = acc[i][1] + bb[1];
            o.z = acc[i][2] + bb[2]; o.w = acc[i][3] + bb[3];
            *(float4*)(C + (size_t)row * ldc + n0 + (tx << 2)) = o;
        }
    }
}

// ---------------- graph prep ----------------
__global__ void k_count(const int* __restrict__ dst, int* __restrict__ cnt) {
    int e = blockIdx.x * 256 + threadIdx.x;
    if (e < NE) atomicAdd(&cnt[dst[e]], 1);
}

__global__ __launch_bounds__(1024) void k_scan(const int* __restrict__ cnt, int* __restrict__ offs,
                                               float* __restrict__ amp, float* __restrict__ ramp) {
    __shared__ int part[1024];
    const int t = threadIdx.x;
    const int base = t * 4;
    int loc[4]; int s = 0;
#pragma unroll
    for (int i = 0; i < 4; ++i) { int v = (base + i < NN) ? cnt[base + i] : 0; loc[i] = s; s += v; }
    part[t] = s;
    __syncthreads();
    for (int o = 1; o < 1024; o <<= 1) {
        int v = (t >= o) ? part[t - o] : 0;
        __syncthreads();
        part[t] += v;
        __syncthreads();
    }
    const int pre = (t > 0) ? part[t - 1] : 0;
#pragma unroll
    for (int i = 0; i < 4; ++i) if (base + i < NN) offs[base + i] = pre + loc[i];
    if (t == 1023) offs[NN] = part[1023];
    for (int n = t; n < NN; n += 1024) {
        float deg = fmaxf((float)cnt[n], 1.0f);
        float a = logf(deg + 1.0f) / AVGLOG;
        amp[n] = a; ramp[n] = 1.0f / a;
    }
}

__global__ void k_fill(const int* __restrict__ src, const int* __restrict__ dst,
                       const int* __restrict__ sgn, const int* __restrict__ offs,
                       int* __restrict__ fill, int* __restrict__ esrc, int* __restrict__ esgn) {
    int e = blockIdx.x * 256 + threadIdx.x;
    if (e < NE) {
        int d = dst[e];
        int pos = offs[d] + atomicAdd(&fill[d], 1);
        esrc[pos] = src[e];
        esgn[pos] = sgn[e];
    }
}

// ---------------- node features ----------------
__global__ void k_build_x(const float* __restrict__ nemb, const float* __restrict__ acts,
                          const float* __restrict__ pew, const float* __restrict__ peb,
                          const int* __restrict__ gidx, float* __restrict__ X) {
    int idx = blockIdx.x * 256 + threadIdx.x;
    int n = idx >> 9, d = idx & 511;
    X[idx] = nemb[(size_t)gidx[n] * DD + d] + acts[n * 2] * pew[d] + acts[n * 2 + 1] * pew[DD + d] + peb[d];
}

// ek[k][d] = edge_emb_w[k] @ edge_enc_w[l] + edge_enc_b[l]
__global__ void k_ek(const float* __restrict__ eemb, const float* __restrict__ eew,
                     const float* __restrict__ eeb, float* __restrict__ EK) {
    int idx = blockIdx.x * 256 + threadIdx.x;  // 0..1023
    int k = idx >> 9, d = idx & 511;
    float s = eeb[d];
    for (int f = 0; f < 50; ++f) s += eemb[k * 50 + f] * eew[(size_t)f * DD + d];
    EK[idx] = s;
}

// em[k][t*512+d] = ek[k] @ We[t] + pre_b[t]   (We = pre_w rows 1024..1535)
__global__ void k_em(const float* __restrict__ EK, const float* __restrict__ pw,
                     const float* __restrict__ pb, float* __restrict__ EM) {
    int idx = blockIdx.x * 256 + threadIdx.x;  // 0..4095
    int k = idx >> 11, g = idx & 2047;
    int t = g >> 9, d = g & 511;
    const float* B = pw + ((size_t)t * 1536 + 1024) * DD + d;
    const float* ek = EK + k * DD;
    float s = pb[g];
    for (int f = 0; f < DD; ++f) s += ek[f] * B[(size_t)f * DD];
    EM[idx] = s;
}

// ---------------- GEMM wrappers ----------------
// xi[n][t][d] = x@Wi[t], xj = x@Wj[t];  z: t = z&3, half = z>>2
__global__ __launch_bounds__(256) void k_pre(const float* __restrict__ X, const float* __restrict__ pw,
                                             float* __restrict__ XI, float* __restrict__ XJ) {
    int z = blockIdx.z; int t = z & 3, half = z >> 2;
    const float* B = pw + ((size_t)t * 1536 + (size_t)half * DD) * DD;
    float* C = (half ? XJ : XI) + t * DD;
    gemm_core(X, DD, B, DD, C, TD, NN, DD, nullptr);
}

// z in 0..15: t = z&3, w = z>>2 (0: x@P0 -> GX; 1..3: A@P{1,2,3} -> G1..G3)
__global__ __launch_bounds__(256) void k_post(const float* __restrict__ X, const float* __restrict__ AB,
                                              const float* __restrict__ pw,
                                              float* __restrict__ GX, float* __restrict__ G1,
                                              float* __restrict__ G2, float* __restrict__ G3) {
    int z = blockIdx.z; int t = z & 3, w = z >> 2;
    const float* Aop; int lda, K, f0; float* C;
    if (w == 0) { Aop = X; lda = DD; K = DD; f0 = 0; C = GX; }
    else {
        Aop = AB + t * TD; lda = AD; K = TD; f0 = DD + (w - 1) * TD;
        C = (w == 1) ? G1 : (w == 2 ? G2 : G3);
    }
    const float* B = pw + ((size_t)t * 6656 + f0) * FO;
    gemm_core(Aop, lda, B, FO, C + t * FO, DD, NN, K, nullptr);
}

__global__ __launch_bounds__(256) void k_lin(const float* __restrict__ O, const float* __restrict__ Wl,
                                             const float* __restrict__ bl, float* __restrict__ H) {
    gemm_core(O, DD, Wl, DD, H, DD, NN, DD, bl);
}

// ---------------- aggregation: one block per dst node ----------------
__global__ __launch_bounds__(256) void k_agg(const float* __restrict__ XI, const float* __restrict__ XJ,
                                             const float* __restrict__ EM, const int* __restrict__ offs,
                                             const int* __restrict__ cnt, const int* __restrict__ esrc,
                                             const int* __restrict__ esgn, float* __restrict__ AB) {
    const int n = blockIdx.x;
    const int g = threadIdx.x * 8;  // 0..2040, (t,d) flat
    float xid[8], em0[8], em1[8];
    *(float4*)&xid[0] = *(const float4*)&XI[(size_t)n * TD + g];
    *(float4*)&xid[4] = *(const float4*)&XI[(size_t)n * TD + g + 4];
    *(float4*)&em0[0] = *(const float4*)&EM[g];
    *(float4*)&em0[4] = *(const float4*)&EM[g + 4];
    *(float4*)&em1[0] = *(const float4*)&EM[TD + g];
    *(float4*)&em1[4] = *(const float4*)&EM[TD + g + 4];
    float s1[8], s2[8], mn[8], mx[8];
#pragma unroll
    for (int i = 0; i < 8; ++i) { s1[i] = 0.f; s2[i] = 0.f; mn[i] = FLT_MAX; mx[i] = -FLT_MAX; }
    const int j0 = offs[n], j1 = offs[n + 1];
    for (int j = j0; j < j1; ++j) {
        const int s = esrc[j];
        const int sg = esgn[j];
        float xv[8];
        *(float4*)&xv[0] = *(const float4*)&XJ[(size_t)s * TD + g];
        *(float4*)&xv[4] = *(const float4*)&XJ[(size_t)s * TD + g + 4];
#pragma unroll
        for (int i = 0; i < 8; ++i) {
            float m = xid[i] + xv[i] + (sg ? em1[i] : em0[i]);
            s1[i] += m; s2[i] += m * m;
            mn[i] = fminf(mn[i], m); mx[i] = fmaxf(mx[i], m);
        }
    }
    const int c = cnt[n];
    const float deg = fmaxf((float)c, 1.0f);
    const float rdeg = 1.0f / deg;
    float mean[8], sd[8];
#pragma unroll
    for (int i = 0; i < 8; ++i) {
        mean[i] = s1[i] * rdeg;
        float var = s2[i] * rdeg - mean[i] * mean[i];
        sd[i] = sqrtf(fmaxf(var, 0.f) + EPS_STD_);
        if (c == 0) { mn[i] = 0.f; mx[i] = 0.f; }
    }
    const int t = g >> 9, d = g & 511;
    float* base = AB + (size_t)n * AD + (size_t)t * 2048 + d;
    *(float4*)(base + 0 * DD) = *(float4*)&mean[0]; *(float4*)(base + 0 * DD + 4) = *(float4*)&mean[4];
    *(float4*)(base + 1 * DD) = *(float4*)&mn[0];   *(float4*)(base + 1 * DD + 4) = *(float4*)&mn[4];
    *(float4*)(base + 2 * DD) = *(float4*)&mx[0];   *(float4*)(base + 2 * DD + 4) = *(float4*)&mx[4];
    *(float4*)(base + 3 * DD) = *(float4*)&sd[0];   *(float4*)(base + 3 * DD + 4) = *(float4*)&sd[4];
}

// o = GX + G1 + amp*G2 + (1/amp)*G3 + post_b
__global__ void k_combine(const float* __restrict__ GX, const float* __restrict__ G1,
                          const float* __restrict__ G2, const float* __restrict__ G3,
                          const float* __restrict__ amp, const float* __restrict__ ramp,
                          const float* __restrict__ pb, float* __restrict__ O) {
    int idx = blockIdx.x * 256 + threadIdx.x;
    int n = idx >> 9, col = idx & 511;
    O[idx] = GX[idx] + G1[idx] + amp[n] * G2[idx] + ramp[n] * G3[idx] + pb[col];
}

// ---------------- batchnorm ----------------
__global__ void k_bnstat(const float* __restrict__ H, float* __restrict__ BN) {
    int cidx = blockIdx.x * 256 + threadIdx.x;  // column 0..511
    int r0 = blockIdx.y * 125;
    float s = 0.f, q = 0.f;
    for (int r = r0; r < r0 + 125; ++r) { float v = H[(size_t)r * DD + cidx]; s += v; q += v * v; }
    atomicAdd(&BN[cidx], s); atomicAdd(&BN[DD + cidx], q);
}

__global__ void k_bnapply(const float* __restrict__ H, const float* __restrict__ BN,
                          const float* __restrict__ gamma, const float* __restrict__ beta,
                          float* __restrict__ X) {
    int idx = blockIdx.x * 256 + threadIdx.x;
    int d = idx & 511;
    float mu = BN[d] * (1.0f / NN);
    float var = BN[DD + d] * (1.0f / NN) - mu * mu;
    float v = gamma[d] * (H[idx] - mu) * rsqrtf(var + EPS_BN_) + beta[d];
    X[idx] = fmaxf(v, 0.f);
}

// ---------------- readout ----------------
__global__ void k_pool(const float* __restrict__ X, const int* __restrict__ batch, float* __restrict__ PL) {
    int idx = blockIdx.x * 256 + threadIdx.x;
    int n = idx >> 9, d = idx & 511;
    atomicAdd(&PL[(size_t)batch[n] * DD + d], X[idx]);
}

__global__ void k_fc1(const float* __restrict__ PL, const float* __restrict__ W1,
                      const float* __restrict__ b1, const float* __restrict__ pa, float* __restrict__ Z) {
    int idx = blockIdx.x * 256 + threadIdx.x;  // 0..32767
    int g = idx >> 10, j = idx & 1023;
    float s = b1[j];
    const float* p = PL + (size_t)g * DD;
    for (int f = 0; f < DD; ++f) s += p[f] * W1[(size_t)f * 1024 + j];
    float a = *pa;
    Z[idx] = s > 0.f ? s : a * s;
}

__global__ __launch_bounds__(64) void k_out(const float* __restrict__ Z, const float* __restrict__ Wo,
                                            const float* __restrict__ bo, float* __restrict__ out) {
    int g = blockIdx.x, t = threadIdx.x;
    float part[NC];
#pragma unroll
    for (int c = 0; c < NC; ++c) part[c] = 0.f;
    for (int f = t; f < 1024; f += 64) {
        float zv = Z[g * 1024 + f];
#pragma unroll
        for (int c = 0; c < NC; ++c) part[c] += zv * Wo[(size_t)f * NC + c];
    }
#pragma unroll
    for (int off = 32; off > 0; off >>= 1)
#pragma unroll
        for (int c = 0; c < NC; ++c) part[c] += __shfl_down(part[c], off);
    if (t == 0) {
        float lg[NC], mxv = -FLT_MAX;
#pragma unroll
        for (int c = 0; c < NC; ++c) { lg[c] = part[c] + bo[c]; mxv = fmaxf(mxv, lg[c]); }
        float se = 0.f;
#pragma unroll
        for (int c = 0; c < NC; ++c) se += expf(lg[c] - mxv);
        float lse = mxv + logf(se);
#pragma unroll
        for (int c = 0; c < NC; ++c) out[g * NC + c] = lg[c] - lse;
    }
}

extern "C" void kernel_launch(void* const* d_in, const int* in_sizes, int n_in,
                              void* d_out, int out_size, void* d_ws, size_t ws_size,
                              hipStream_t stream) {
    const float* node_emb_w = (const float*)d_in[0];
    const float* edge_emb_w = (const float*)d_in[1];
    const float* pe_w   = (const float*)d_in[2];
    const float* pe_b   = (const float*)d_in[3];
    const float* edge_enc_w = (const float*)d_in[4];
    const float* edge_enc_b = (const float*)d_in[5];
    const float* pre_w  = (const float*)d_in[6];
    const float* pre_b  = (const float*)d_in[7];
    const float* post_w = (const float*)d_in[8];
    const float* post_b = (const float*)d_in[9];
    const float* lin_w  = (const float*)d_in[10];
    const float* lin_b  = (const float*)d_in[11];
    const float* bn_gamma = (const float*)d_in[12];
    const float* bn_beta  = (const float*)d_in[13];
    const float* acts   = (const float*)d_in[14];
    const float* fc1_w  = (const float*)d_in[15];
    const float* fc1_b  = (const float*)d_in[16];
    const float* fc_out_w = (const float*)d_in[17];
    const float* fc_out_b = (const float*)d_in[18];
    const float* prelu_a  = (const float*)d_in[19];
    const int* global_idx = (const int*)d_in[20];
    const int* sgn        = (const int*)d_in[21];
    const int* edge_index = (const int*)d_in[22];
    const int* batch      = (const int*)d_in[23];
    float* out = (float*)d_out;

    float* W = (float*)d_ws;
    size_t off = 0;
    float* X  = W + off; off += (size_t)NN * DD;
    float* H  = W + off; off += (size_t)NN * DD;
    float* XI = W + off; off += (size_t)NN * TD;
    float* XJ = W + off; off += (size_t)NN * TD;
    float* AB = W + off; off += (size_t)NN * AD;
    float* GX = W + off; off += (size_t)NN * DD;
    float* G1 = W + off; off += (size_t)NN * DD;
    float* G2 = W + off; off += (size_t)NN * DD;
    float* G3 = W + off; off += (size_t)NN * DD;
    float* O  = W + off; off += (size_t)NN * DD;
    float* EK = W + off; off += 2 * DD;
    float* EM = W + off; off += 2 * TD;
    float* BN = W + off; off += 2 * DD;
    float* PL = W + off; off += NG * DD;
    float* ZB = W + off; off += NG * 1024;
    float* AMP  = W + off; off += NN;
    float* RAMP = W + off; off += NN;
    int* CNT  = (int*)(W + off); off += NN;
    int* OFFS = (int*)(W + off); off += NN + 1;
    int* FILL = (int*)(W + off); off += NN + 1;
    int* ESRC = (int*)(W + off); off += NE;
    int* ESGN = (int*)(W + off); off += NE;

    const int* src = edge_index;
    const int* dst = edge_index + NE;

    hipMemsetAsync(CNT, 0, NN * sizeof(int), stream);
    hipMemsetAsync(FILL, 0, NN * sizeof(int), stream);
    k_count<<<(NE + 255) / 256, 256, 0, stream>>>(dst, CNT);
    k_scan<<<1, 1024, 0, stream>>>(CNT, OFFS, AMP, RAMP);
    k_fill<<<(NE + 255) / 256, 256, 0, stream>>>(src, dst, sgn, OFFS, FILL, ESRC, ESGN);
    k_build_x<<<NN * DD / 256, 256, 0, stream>>>(node_emb_w, acts, pe_w, pe_b, global_idx, X);

    for (int l = 0; l < 2; ++l) {
        const float* pre_w_l  = pre_w  + (size_t)l * NT * 3 * DD * DD;
        const float* pre_b_l  = pre_b  + (size_t)l * NT * DD;
        const float* post_w_l = post_w + (size_t)l * NT * 6656 * FO;
        const float* post_b_l = post_b + (size_t)l * NT * FO;
        const float* lin_w_l  = lin_w  + (size_t)l * DD * DD;
        const float* lin_b_l  = lin_b  + (size_t)l * DD;
        const float* eew_l    = edge_enc_w + (size_t)l * 50 * DD;
        const float* eeb_l    = edge_enc_b + (size_t)l * DD;

        k_ek<<<4, 256, 0, stream>>>(edge_emb_w, eew_l, eeb_l, EK);
        k_em<<<16, 256, 0, stream>>>(EK, pre_w_l, pre_b_l, EM);
        k_pre<<<dim3(8, 63, 8), 256, 0, stream>>>(X, pre_w_l, XI, XJ);
        k_agg<<<NN, 256, 0, stream>>>(XI, XJ, EM, OFFS, CNT, ESRC, ESGN, AB);
        k_post<<<dim3(2, 63, 16), 256, 0, stream>>>(X, AB, post_w_l, GX, G1, G2, G3);
        k_combine<<<NN * DD / 256, 256, 0, stream>>>(GX, G1, G2, G3, AMP, RAMP, post_b_l, O);
        k_lin<<<dim3(8, 63, 1), 256, 0, stream>>>(O, lin_w_l, lin_b_l, H);
        hipMemsetAsync(BN, 0, 2 * DD * sizeof(float), stream);
        k_bnstat<<<dim3(2, 32), 256, 0, stream>>>(H, BN);
        k_bnapply<<<NN * DD / 256, 256, 0, stream>>>(H, BN, bn_gamma + (size_t)l * DD, bn_beta + (size_t)l * DD, X);
    }

    hipMemsetAsync(PL, 0, NG * DD * sizeof(float), stream);
    k_pool<<<NN * DD / 256, 256, 0, stream>>>(X, batch, PL);
    k_fc1<<<NG * 1024 / 256, 256, 0, stream>>>(PL, fc1_w, fc1_b, prelu_a, ZB);
    k_out<<<NG, 64, 0, stream>>>(ZB, fc_out_w, fc_out_b, out);
}

// Round 2
// 615.602 us; speedup vs baseline: 2.7723x; 2.7723x over previous
//
#include <hip/hip_runtime.h>
#include <hip/hip_bf16.h>
#include <float.h>

#define NN 4000      // nodes
#define NE 20000     // edges
#define DD 512       // D
#define NT 4         // towers
#define FO 128       // F_OUT
#define NG 32
#define NC 10
#define AVGLOG 1.2548916493836102f
#define EPS_STD_ 1e-5f
#define EPS_BN_ 1e-5f

typedef __bf16 bf16x8 __attribute__((ext_vector_type(8)));
typedef float  f32x4  __attribute__((ext_vector_type(4)));

__device__ __forceinline__ void async_copy16(const void* g, void* l) {
    __builtin_amdgcn_global_load_lds((const __attribute__((address_space(1))) void*)g,
                                     (__attribute__((address_space(3))) void*)l, 16, 0, 0);
}

// =============== bf16 MFMA GEMM: C[M][N] = A[M][K](row,lda) x BT[N][K](row,K) ===============
// 256 thr = 4 waves, tile 128x128, BK=32, each wave 64x64 via 4x4 of 16x16x32 MFMA.
template<int OUT_BF16, int HAS_BIAS>
__global__ __launch_bounds__(256) void k_gemm(
    const __bf16* __restrict__ A, int lda, long zA,
    const __bf16* __restrict__ BT, long zB,
    void* __restrict__ Cv, int ldc, long zC,
    const float* __restrict__ bias,
    int M, int K)
{
    A  += (size_t)blockIdx.z * zA;
    BT += (size_t)blockIdx.z * zB;
    const int m0 = blockIdx.y * 128;
    const int n0 = blockIdx.x * 128;
    __shared__ __bf16 As[128 * 32];
    __shared__ __bf16 Bs[128 * 32];
    const int tid = threadIdx.x;
    const int wave = tid >> 6, lane = tid & 63;
    const int wm = (wave >> 1) * 64, wn = (wave & 1) * 64;
    const int fr = lane & 15, fq = lane >> 4;   // frag row/col, quad
    const int fk = fq * 8;                      // frag k elem offset
    const int srow = lane >> 2;                 // staging row within 16-row chunk
    const int skc = (lane & 3) * 8;             // staging k elem offset

    f32x4 acc[4][4];
    const f32x4 zero = {0.f, 0.f, 0.f, 0.f};
#pragma unroll
    for (int i = 0; i < 4; ++i)
#pragma unroll
        for (int j = 0; j < 4; ++j) acc[i][j] = zero;

    for (int k0 = 0; k0 < K; k0 += 32) {
#pragma unroll
        for (int q = 0; q < 2; ++q) {
            const int row = wave * 32 + q * 16 + srow;   // 0..127
            int ar = m0 + row; if (ar > M - 1) ar = M - 1;
            async_copy16(A + (size_t)ar * lda + k0 + skc, As + wave * 1024 + q * 512);
            async_copy16(BT + (size_t)(n0 + row) * K + k0 + skc, Bs + wave * 1024 + q * 512);
        }
        __syncthreads();
        bf16x8 af[4], bfr[4];
#pragma unroll
        for (int mi = 0; mi < 4; ++mi) af[mi]  = *(const bf16x8*)(As + (wm + mi * 16 + fr) * 32 + fk);
#pragma unroll
        for (int ni = 0; ni < 4; ++ni) bfr[ni] = *(const bf16x8*)(Bs + (wn + ni * 16 + fr) * 32 + fk);
#pragma unroll
        for (int mi = 0; mi < 4; ++mi)
#pragma unroll
            for (int ni = 0; ni < 4; ++ni)
                acc[mi][ni] = __builtin_amdgcn_mfma_f32_16x16x32_bf16(af[mi], bfr[ni], acc[mi][ni], 0, 0, 0);
        __syncthreads();
    }
    float* Cf = (float*)Cv; __bf16* Cb = (__bf16*)Cv;
    const size_t cz = (size_t)blockIdx.z * zC;
#pragma unroll
    for (int mi = 0; mi < 4; ++mi) {
#pragma unroll
        for (int ni = 0; ni < 4; ++ni) {
            const int col = n0 + wn + ni * 16 + fr;
            const int rb = m0 + wm + mi * 16 + fq * 4;
            const float bv = HAS_BIAS ? bias[col] : 0.f;
#pragma unroll
            for (int r = 0; r < 4; ++r) {
                const int rowc = rb + r;
                if (rowc < M) {
                    const float v = acc[mi][ni][r] + bv;
                    if (OUT_BF16) Cb[cz + (size_t)rowc * ldc + col] = (__bf16)v;
                    else          Cf[cz + (size_t)rowc * ldc + col] = v;
                }
            }
        }
    }
}

// =============== weight transpose/convert fp32 -> bf16 (N x K layouts) ===============
__device__ __forceinline__ void tr32(const float* __restrict__ S, int sld,
                                     __bf16* __restrict__ D, int dld) {
    __shared__ float t[32][33];
    const int x = threadIdx.x, y0 = threadIdx.y * 4;
#pragma unroll
    for (int i = 0; i < 4; ++i) t[y0 + i][x] = S[(size_t)(y0 + i) * sld + x];
    __syncthreads();
#pragma unroll
    for (int i = 0; i < 4; ++i) D[(size_t)(y0 + i) * dld + x] = (__bf16)t[x][y0 + i];
}

// WPRET[col][f], col = half*2048 + t*512 + d  (half 0=Wi,1=Wj,2=We)
__global__ void k_tr_pre(const float* __restrict__ pw, __bf16* __restrict__ WPRET) {
    const int t = blockIdx.z & 3, half = blockIdx.z >> 2;  // z = half*4+t, 12 jobs
    const float* S = pw + ((size_t)(t * 1536 + half * 512 + blockIdx.y * 32)) * 512 + blockIdx.x * 32;
    __bf16* D = WPRET + ((size_t)(half * 2048 + t * 512 + blockIdx.x * 32)) * 512 + blockIdx.y * 32;
    tr32(S, 512, D, 512);
}

// W0T[t*128+o][f] <- post_w[t][f][o]  (f<512)
__global__ void k_tr_w0(const float* __restrict__ pow_, __bf16* __restrict__ W0T) {
    const int t = blockIdx.z;
    const float* S = pow_ + ((size_t)(t * 6656 + blockIdx.y * 32)) * 128 + blockIdx.x * 32;
    __bf16* D = W0T + ((size_t)(t * 128 + blockIdx.x * 32)) * 512 + blockIdx.y * 32;
    tr32(S, 128, D, 512);
}

// WTT[t][w*128+o][f] <- post_w[t][512 + w*2048 + f][o]
__global__ void k_tr_wt(const float* __restrict__ pow_, __bf16* __restrict__ WTT) {
    const int t = blockIdx.z / 3, w = blockIdx.z % 3;
    const float* S = pow_ + ((size_t)(t * 6656 + 512 + w * 2048 + blockIdx.y * 32)) * 128 + blockIdx.x * 32;
    __bf16* D = WTT + (size_t)t * 384 * 2048 + ((size_t)(w * 128 + blockIdx.x * 32)) * 2048 + blockIdx.y * 32;
    tr32(S, 128, D, 2048);
}

__global__ void k_tr_lin(const float* __restrict__ lw, __bf16* __restrict__ WLINT) {
    const float* S = lw + (size_t)blockIdx.y * 32 * 512 + blockIdx.x * 32;
    __bf16* D = WLINT + (size_t)blockIdx.x * 32 * 512 + blockIdx.y * 32;
    tr32(S, 512, D, 512);
}

// ---------------- graph prep ----------------
__global__ void k_count(const int* __restrict__ dst, int* __restrict__ cnt) {
    int e = blockIdx.x * 256 + threadIdx.x;
    if (e < NE) atomicAdd(&cnt[dst[e]], 1);
}

__global__ __launch_bounds__(1024) void k_scan(const int* __restrict__ cnt, int* __restrict__ offs,
                                               float* __restrict__ amp, float* __restrict__ ramp) {
    __shared__ int part[1024];
    const int t = threadIdx.x;
    const int base = t * 4;
    int loc[4]; int s = 0;
#pragma unroll
    for (int i = 0; i < 4; ++i) { int v = (base + i < NN) ? cnt[base + i] : 0; loc[i] = s; s += v; }
    part[t] = s;
    __syncthreads();
    for (int o = 1; o < 1024; o <<= 1) {
        int v = (t >= o) ? part[t - o] : 0;
        __syncthreads();
        part[t] += v;
        __syncthreads();
    }
    const int pre = (t > 0) ? part[t - 1] : 0;
#pragma unroll
    for (int i = 0; i < 4; ++i) if (base + i < NN) offs[base + i] = pre + loc[i];
    if (t == 1023) offs[NN] = part[1023];
    for (int n = t; n < NN; n += 1024) {
        float deg = fmaxf((float)cnt[n], 1.0f);
        float a = logf(deg + 1.0f) / AVGLOG;
        amp[n] = a; ramp[n] = 1.0f / a;
    }
}

__global__ void k_fill(const int* __restrict__ src, const int* __restrict__ dst,
                       const int* __restrict__ sgn, const int* __restrict__ offs,
                       int* __restrict__ fill, int* __restrict__ esrc, int* __restrict__ esgn) {
    int e = blockIdx.x * 256 + threadIdx.x;
    if (e < NE) {
        int d = dst[e];
        int pos = offs[d] + atomicAdd(&fill[d], 1);
        esrc[pos] = src[e];
        esgn[pos] = sgn[e];
    }
}

// ---------------- node features ----------------
__global__ void k_build_x(const float* __restrict__ nemb, const float* __restrict__ acts,
                          const float* __restrict__ pew, const float* __restrict__ peb,
                          const int* __restrict__ gidx, float* __restrict__ X, __bf16* __restrict__ XB) {
    int idx = blockIdx.x * 256 + threadIdx.x;
    int n = idx >> 9, d = idx & 511;
    float v = nemb[(size_t)gidx[n] * DD + d] + acts[n * 2] * pew[d] + acts[n * 2 + 1] * pew[DD + d] + peb[d];
    X[idx] = v; XB[idx] = (__bf16)v;
}

// ek[k][d] = edge_emb_w[k] @ edge_enc_w[l] + edge_enc_b[l]
__global__ void k_ek(const float* __restrict__ eemb, const float* __restrict__ eew,
                     const float* __restrict__ eeb, float* __restrict__ EK) {
    int idx = blockIdx.x * 256 + threadIdx.x;  // 0..1023
    int k = idx >> 9, d = idx & 511;
    float s = eeb[d];
    for (int f = 0; f < 50; ++f) s += eemb[k * 50 + f] * eew[(size_t)f * DD + d];
    EK[idx] = s;
}

// EM[k][t*512+d] = ek[k] @ We[t] + pre_b[t]  (We rows = WPRET half=2)
__global__ void k_em2(const float* __restrict__ EK, const __bf16* __restrict__ WPRET,
                      const float* __restrict__ pb, float* __restrict__ EM) {
    int idx = blockIdx.x * 256 + threadIdx.x;  // 0..4095
    int k = idx >> 11, g = idx & 2047;
    const __bf16* w = WPRET + (size_t)(4096 + g) * 512;
    const float* ek = EK + k * 512;
    float s = pb[g];
    for (int f = 0; f < 512; f += 8) {
        bf16x8 wv = *(const bf16x8*)(w + f);
        float4 e0 = *(const float4*)(ek + f);
        float4 e1 = *(const float4*)(ek + f + 4);
        s += e0.x * (float)wv[0] + e0.y * (float)wv[1] + e0.z * (float)wv[2] + e0.w * (float)wv[3]
           + e1.x * (float)wv[4] + e1.y * (float)wv[5] + e1.z * (float)wv[6] + e1.w * (float)wv[7];
    }
    EM[idx] = s;
}

// ---------------- aggregation: one block per dst node ----------------
__global__ __launch_bounds__(256) void k_agg(const __bf16* __restrict__ XIJ, const float* __restrict__ EM,
                                             const int* __restrict__ offs, const int* __restrict__ cnt,
                                             const int* __restrict__ esrc, const int* __restrict__ esgn,
                                             __bf16* __restrict__ AB) {
    const int n = blockIdx.x;
    const int g = threadIdx.x * 8;  // (t,d) flat, 8 contiguous d
    float xid[8], em0[8], em1[8];
    {
        bf16x8 xb = *(const bf16x8*)(XIJ + (size_t)n * 4096 + g);
#pragma unroll
        for (int i = 0; i < 8; ++i) xid[i] = (float)xb[i];
    }
    *(float4*)&em0[0] = *(const float4*)&EM[g];
    *(float4*)&em0[4] = *(const float4*)&EM[g + 4];
    *(float4*)&em1[0] = *(const float4*)&EM[2048 + g];
    *(float4*)&em1[4] = *(const float4*)&EM[2048 + g + 4];
    float s1[8], s2[8], mn[8], mx[8];
#pragma unroll
    for (int i = 0; i < 8; ++i) { s1[i] = 0.f; s2[i] = 0.f; mn[i] = FLT_MAX; mx[i] = -FLT_MAX; }
    const int j0 = offs[n], j1 = offs[n + 1];
    for (int j = j0; j < j1; ++j) {
        const int s = esrc[j];
        const int sg = esgn[j];
        bf16x8 xv = *(const bf16x8*)(XIJ + (size_t)s * 4096 + 2048 + g);
#pragma unroll
        for (int i = 0; i < 8; ++i) {
            float m = xid[i] + (float)xv[i] + (sg ? em1[i] : em0[i]);
            s1[i] += m; s2[i] += m * m;
            mn[i] = fminf(mn[i], m); mx[i] = fmaxf(mx[i], m);
        }
    }
    const int c = cnt[n];
    const float deg = fmaxf((float)c, 1.0f);
    const float rdeg = 1.0f / deg;
    bf16x8 vmean, vmn, vmx, vsd;
#pragma unroll
    for (int i = 0; i < 8; ++i) {
        float mean = s1[i] * rdeg;
        float var = s2[i] * rdeg - mean * mean;
        float sd = sqrtf(fmaxf(var, 0.f) + EPS_STD_);
        float mnv = (c == 0) ? 0.f : mn[i];
        float mxv = (c == 0) ? 0.f : mx[i];
        vmean[i] = (__bf16)mean; vmn[i] = (__bf16)mnv; vmx[i] = (__bf16)mxv; vsd[i] = (__bf16)sd;
    }
    const int t = g >> 9, d = g & 511;
    __bf16* base = AB + (size_t)n * 8192 + (size_t)t * 2048 + d;
    *(bf16x8*)(base + 0 * DD) = vmean;
    *(bf16x8*)(base + 1 * DD) = vmn;
    *(bf16x8*)(base + 2 * DD) = vmx;
    *(bf16x8*)(base + 3 * DD) = vsd;
}

// O[n][t*128+o] = GX + GW1 + amp*GW2 + ramp*GW3 + post_b  -> bf16
__global__ void k_combine(const float* __restrict__ GX, const float* __restrict__ GW,
                          const float* __restrict__ amp, const float* __restrict__ ramp,
                          const float* __restrict__ pb, __bf16* __restrict__ OB) {
    int idx = blockIdx.x * 256 + threadIdx.x;
    int n = idx >> 9, c = idx & 511;
    int t = c >> 7, o = c & 127;
    const float* gw = GW + (size_t)t * NN * 384 + (size_t)n * 384;
    float v = GX[idx] + gw[o] + amp[n] * gw[128 + o] + ramp[n] * gw[256 + o] + pb[c];
    OB[idx] = (__bf16)v;
}

// ---------------- batchnorm ----------------
__global__ void k_bnstat(const float* __restrict__ H, float* __restrict__ BN) {
    int cidx = blockIdx.x * 256 + threadIdx.x;  // column 0..511
    int r0 = blockIdx.y * 125;
    float s = 0.f, q = 0.f;
    for (int r = r0; r < r0 + 125; ++r) { float v = H[(size_t)r * DD + cidx]; s += v; q += v * v; }
    atomicAdd(&BN[cidx], s); atomicAdd(&BN[DD + cidx], q);
}

__global__ void k_bnapply(const float* __restrict__ H, const float* __restrict__ BN,
                          const float* __restrict__ gamma, const float* __restrict__ beta,
                          float* __restrict__ X, __bf16* __restrict__ XB) {
    int idx = blockIdx.x * 256 + threadIdx.x;
    int d = idx & 511;
    float mu = BN[d] * (1.0f / NN);
    float var = BN[DD + d] * (1.0f / NN) - mu * mu;
    float v = gamma[d] * (H[idx] - mu) * rsqrtf(var + EPS_BN_) + beta[d];
    v = fmaxf(v, 0.f);
    X[idx] = v; XB[idx] = (__bf16)v;
}

// ---------------- readout ----------------
__global__ void k_pool(const float* __restrict__ X, const int* __restrict__ batch, float* __restrict__ PL) {
    int idx = blockIdx.x * 256 + threadIdx.x;
    int n = idx >> 9, d = idx & 511;
    atomicAdd(&PL[(size_t)batch[n] * DD + d], X[idx]);
}

__global__ void k_fc1(const float* __restrict__ PL, const float* __restrict__ W1,
                      const float* __restrict__ b1, const float* __restrict__ pa, float* __restrict__ Z) {
    int idx = blockIdx.x * 256 + threadIdx.x;  // 0..32767
    int g = idx >> 10, j = idx & 1023;
    float s = b1[j];
    const float* p = PL + (size_t)g * DD;
    for (int f = 0; f < DD; ++f) s += p[f] * W1[(size_t)f * 1024 + j];
    float a = *pa;
    Z[idx] = s > 0.f ? s : a * s;
}

__global__ __launch_bounds__(64) void k_out(const float* __restrict__ Z, const float* __restrict__ Wo,
                                            const float* __restrict__ bo, float* __restrict__ out) {
    int g = blockIdx.x, t = threadIdx.x;
    float part[NC];
#pragma unroll
    for (int c = 0; c < NC; ++c) part[c] = 0.f;
    for (int f = t; f < 1024; f += 64) {
        float zv = Z[g * 1024 + f];
#pragma unroll
        for (int c = 0; c < NC; ++c) part[c] += zv * Wo[(size_t)f * NC + c];
    }
#pragma unroll
    for (int off = 32; off > 0; off >>= 1)
#pragma unroll
        for (int c = 0; c < NC; ++c) part[c] += __shfl_down(part[c], off);
    if (t == 0) {
        float lg[NC], mxv = -FLT_MAX;
#pragma unroll
        for (int c = 0; c < NC; ++c) { lg[c] = part[c] + bo[c]; mxv = fmaxf(mxv, lg[c]); }
        float se = 0.f;
#pragma unroll
        for (int c = 0; c < NC; ++c) se += expf(lg[c] - mxv);
        float lse = mxv + logf(se);
#pragma unroll
        for (int c = 0; c < NC; ++c) out[g * NC + c] = lg[c] - lse;
    }
}

extern "C" void kernel_launch(void* const* d_in, const int* in_sizes, int n_in,
                              void* d_out, int out_size, void* d_ws, size_t ws_size,
                              hipStream_t stream) {
    const float* node_emb_w = (const float*)d_in[0];
    const float* edge_emb_w = (const float*)d_in[1];
    const float* pe_w   = (const float*)d_in[2];
    const float* pe_b   = (const float*)d_in[3];
    const float* edge_enc_w = (const float*)d_in[4];
    const float* edge_enc_b = (const float*)d_in[5];
    const float* pre_w  = (const float*)d_in[6];
    const float* pre_b  = (const float*)d_in[7];
    const float* post_w = (const float*)d_in[8];
    const float* post_b = (const float*)d_in[9];
    const float* lin_w  = (const float*)d_in[10];
    const float* lin_b  = (const float*)d_in[11];
    const float* bn_gamma = (const float*)d_in[12];
    const float* bn_beta  = (const float*)d_in[13];
    const float* acts   = (const float*)d_in[14];
    const float* fc1_w  = (const float*)d_in[15];
    const float* fc1_b  = (const float*)d_in[16];
    const float* fc_out_w = (const float*)d_in[17];
    const float* fc_out_b = (const float*)d_in[18];
    const float* prelu_a  = (const float*)d_in[19];
    const int* global_idx = (const int*)d_in[20];
    const int* sgn        = (const int*)d_in[21];
    const int* edge_index = (const int*)d_in[22];
    const int* batch      = (const int*)d_in[23];
    float* out = (float*)d_out;

    char* W = (char*)d_ws;
    size_t off = 0;
    auto alloc = [&](size_t bytes) { void* p = W + off; off += (bytes + 63) & ~(size_t)63; return p; };
    float*  X     = (float*)alloc((size_t)NN * DD * 4);
    __bf16* XB    = (__bf16*)alloc((size_t)NN * DD * 2);
    float*  H     = (float*)alloc((size_t)NN * DD * 4);
    __bf16* XIJ   = (__bf16*)alloc((size_t)NN * 4096 * 2);
    __bf16* AB    = (__bf16*)alloc((size_t)NN * 8192 * 2);
    float*  GX    = (float*)alloc((size_t)NN * DD * 4);
    float*  GW    = (float*)alloc((size_t)NT * NN * 384 * 4);
    __bf16* OB    = (__bf16*)alloc((size_t)NN * DD * 2);
    __bf16* WPRET = (__bf16*)alloc((size_t)6144 * 512 * 2);
    __bf16* W0T   = (__bf16*)alloc((size_t)512 * 512 * 2);
    __bf16* WTT   = (__bf16*)alloc((size_t)NT * 384 * 2048 * 2);
    __bf16* WLINT = (__bf16*)alloc((size_t)512 * 512 * 2);
    float*  EK    = (float*)alloc(2 * 512 * 4);
    float*  EM    = (float*)alloc(2 * 2048 * 4);
    float*  BN    = (float*)alloc(2 * 512 * 4);
    float*  PL    = (float*)alloc((size_t)NG * DD * 4);
    float*  ZB    = (float*)alloc((size_t)NG * 1024 * 4);
    float*  AMP   = (float*)alloc(NN * 4);
    float*  RAMP  = (float*)alloc(NN * 4);
    int*    CNT   = (int*)alloc(NN * 4);
    int*    OFFS  = (int*)alloc((NN + 1) * 4);
    int*    FILL  = (int*)alloc(NN * 4);
    int*    ESRC  = (int*)alloc(NE * 4);
    int*    ESGN  = (int*)alloc(NE * 4);

    const int* src = edge_index;
    const int* dst = edge_index + NE;

    hipMemsetAsync(CNT, 0, NN * sizeof(int), stream);
    hipMemsetAsync(FILL, 0, NN * sizeof(int), stream);
    k_count<<<(NE + 255) / 256, 256, 0, stream>>>(dst, CNT);
    k_scan<<<1, 1024, 0, stream>>>(CNT, OFFS, AMP, RAMP);
    k_fill<<<(NE + 255) / 256, 256, 0, stream>>>(src, dst, sgn, OFFS, FILL, ESRC, ESGN);
    k_build_x<<<NN * DD / 256, 256, 0, stream>>>(node_emb_w, acts, pe_w, pe_b, global_idx, X, XB);

    const dim3 tb(32, 8);
    for (int l = 0; l < 2; ++l) {
        const float* pre_w_l  = pre_w  + (size_t)l * NT * 3 * DD * DD;
        const float* pre_b_l  = pre_b  + (size_t)l * NT * DD;
        const float* post_w_l = post_w + (size_t)l * NT * 6656 * FO;
        const float* post_b_l = post_b + (size_t)l * NT * FO;
        const float* lin_w_l  = lin_w  + (size_t)l * DD * DD;
        const float* lin_b_l  = lin_b  + (size_t)l * DD;
        const float* eew_l    = edge_enc_w + (size_t)l * 50 * DD;
        const float* eeb_l    = edge_enc_b + (size_t)l * DD;

        // weight convert/transpose to bf16 N x K
        k_tr_pre<<<dim3(16, 16, 12), tb, 0, stream>>>(pre_w_l, WPRET);
        k_tr_w0 <<<dim3(4, 16, 4),  tb, 0, stream>>>(post_w_l, W0T);
        k_tr_wt <<<dim3(4, 64, 12), tb, 0, stream>>>(post_w_l, WTT);
        k_tr_lin<<<dim3(16, 16, 1), tb, 0, stream>>>(lin_w_l, WLINT);

        k_ek<<<4, 256, 0, stream>>>(edge_emb_w, eew_l, eeb_l, EK);
        k_em2<<<16, 256, 0, stream>>>(EK, WPRET, pre_b_l, EM);

        // XIJ = X @ [Wi|Wj]  (M=4000, K=512, N=4096) -> bf16
        k_gemm<1, 0><<<dim3(32, 32, 1), 256, 0, stream>>>(XB, 512, 0, WPRET, 0, XIJ, 4096, 0, nullptr, NN, 512);
        k_agg<<<NN, 256, 0, stream>>>(XIJ, EM, OFFS, CNT, ESRC, ESGN, AB);
        // GX = X @ W0  (M=4000, K=512, N=512) -> fp32
        k_gemm<0, 0><<<dim3(4, 32, 1), 256, 0, stream>>>(XB, 512, 0, W0T, 0, GX, 512, 0, nullptr, NN, 512);
        // GW[t] = A_t @ [P1|P2|P3]  (M=4000, K=2048, N=384) x4 towers -> fp32
        k_gemm<0, 0><<<dim3(3, 32, 4), 256, 0, stream>>>(AB, 8192, 2048, WTT, (long)384 * 2048, GW, 384, (long)NN * 384, nullptr, NN, 2048);
        k_combine<<<NN * DD / 256, 256, 0, stream>>>(GX, GW, AMP, RAMP, post_b_l, OB);
        // H = O @ lin_w + lin_b  (M=4000, K=512, N=512) -> fp32
        k_gemm<0, 1><<<dim3(4, 32, 1), 256, 0, stream>>>(OB, 512, 0, WLINT, 0, H, 512, 0, lin_b_l, NN, 512);

        hipMemsetAsync(BN, 0, 2 * DD * sizeof(float), stream);
        k_bnstat<<<dim3(2, 32), 256, 0, stream>>>(H, BN);
        k_bnapply<<<NN * DD / 256, 256, 0, stream>>>(H, BN, bn_gamma + (size_t)l * DD, bn_beta + (size_t)l * DD, X, XB);
    }

    hipMemsetAsync(PL, 0, NG * DD * sizeof(float), stream);
    k_pool<<<NN * DD / 256, 256, 0, stream>>>(X, batch, PL);
    k_fc1<<<NG * 1024 / 256, 256, 0, stream>>>(PL, fc1_w, fc1_b, prelu_a, ZB);
    k_out<<<NG, 64, 0, stream>>>(ZB, fc_out_w, fc_out_b, out);
}

// Round 3
// 570.469 us; speedup vs baseline: 2.9917x; 1.0791x over previous
//
#include <hip/hip_runtime.h>
#include <hip/hip_bf16.h>
#include <float.h>

#define NN 4000      // nodes
#define NE 20000     // edges
#define DD 512       // D
#define NT 4         // towers
#define FO 128       // F_OUT
#define NG 32
#define NC 10
#define XGW 4608     // XG row width: 2048 xi + 2048 xj + 512 gx
#define AVGLOG 1.2548916493836102f
#define EPS_STD_ 1e-5f
#define EPS_BN_ 1e-5f

typedef __bf16 bf16x8 __attribute__((ext_vector_type(8)));
typedef float  f32x4  __attribute__((ext_vector_type(4)));

__device__ __forceinline__ void async_copy16(const void* g, void* l) {
    __builtin_amdgcn_global_load_lds((const __attribute__((address_space(1))) void*)g,
                                     (__attribute__((address_space(3))) void*)l, 16, 0, 0);
}

// =============== bf16 MFMA GEMM core: C[M][N] = A[M][K](row,lda) x BT[N][K](row,ldbt) ===============
// 256 thr = 4 waves, tile 128x128, BK=32, each wave 64x64 via 4x4 of 16x16x32 MFMA.
template<int OUT_BF16, int HAS_BIAS>
__device__ __forceinline__ void mfma_core(
    const __bf16* __restrict__ A, int lda,
    const __bf16* __restrict__ BT, int ldbt,
    void* __restrict__ Cv, int ldc,
    const float* __restrict__ bias,
    int M, int K, int m0, int n0)
{
    __shared__ __bf16 As[128 * 32];
    __shared__ __bf16 Bs[128 * 32];
    const int tid = threadIdx.x;
    const int wave = tid >> 6, lane = tid & 63;
    const int wm = (wave >> 1) * 64, wn = (wave & 1) * 64;
    const int fr = lane & 15, fq = lane >> 4;   // frag row, quad
    const int fk = fq * 8;                      // frag k elem offset
    const int srow = lane >> 2;                 // staging row within 16-row chunk
    const int skc = (lane & 3) * 8;             // staging k elem offset

    f32x4 acc[4][4];
    const f32x4 zero = {0.f, 0.f, 0.f, 0.f};
#pragma unroll
    for (int i = 0; i < 4; ++i)
#pragma unroll
        for (int j = 0; j < 4; ++j) acc[i][j] = zero;

    for (int k0 = 0; k0 < K; k0 += 32) {
#pragma unroll
        for (int q = 0; q < 2; ++q) {
            const int row = wave * 32 + q * 16 + srow;   // 0..127
            int ar = m0 + row; if (ar > M - 1) ar = M - 1;
            async_copy16(A + (size_t)ar * lda + k0 + skc, As + wave * 1024 + q * 512);
            async_copy16(BT + (size_t)(n0 + row) * ldbt + k0 + skc, Bs + wave * 1024 + q * 512);
        }
        __syncthreads();
        bf16x8 af[4], bfr[4];
#pragma unroll
        for (int mi = 0; mi < 4; ++mi) af[mi]  = *(const bf16x8*)(As + (wm + mi * 16 + fr) * 32 + fk);
#pragma unroll
        for (int ni = 0; ni < 4; ++ni) bfr[ni] = *(const bf16x8*)(Bs + (wn + ni * 16 + fr) * 32 + fk);
#pragma unroll
        for (int mi = 0; mi < 4; ++mi)
#pragma unroll
            for (int ni = 0; ni < 4; ++ni)
                acc[mi][ni] = __builtin_amdgcn_mfma_f32_16x16x32_bf16(af[mi], bfr[ni], acc[mi][ni], 0, 0, 0);
        __syncthreads();
    }
    float* Cf = (float*)Cv; __bf16* Cb = (__bf16*)Cv;
#pragma unroll
    for (int mi = 0; mi < 4; ++mi) {
#pragma unroll
        for (int ni = 0; ni < 4; ++ni) {
            const int col = n0 + wn + ni * 16 + fr;
            const int rb = m0 + wm + mi * 16 + fq * 4;
            const float bv = HAS_BIAS ? bias[col] : 0.f;
#pragma unroll
            for (int r = 0; r < 4; ++r) {
                const int rowc = rb + r;
                if (rowc < M) {
                    const float v = acc[mi][ni][r] + bv;
                    if (OUT_BF16) Cb[(size_t)rowc * ldc + col] = (__bf16)v;
                    else          Cf[(size_t)rowc * ldc + col] = v;
                }
            }
        }
    }
}

// XG[n][0:4608] = XB @ [Wi|Wj|W0]^T  (K=512) -> bf16
__global__ __launch_bounds__(256) void k_xg(const __bf16* __restrict__ XB, const __bf16* __restrict__ WCAT,
                                            __bf16* __restrict__ XG) {
    mfma_core<1, 0>(XB, 512, WCAT, 512, XG, XGW, nullptr, NN, 512,
                    blockIdx.y * 128, blockIdx.x * 128);
}

// GWP[kh*4+t][n][384] = AB_t[:, kh*1024 : kh*1024+1024] @ WTT_t[:, kh*1024:...]^T
__global__ __launch_bounds__(256) void k_gw(const __bf16* __restrict__ AB, const __bf16* __restrict__ WTT,
                                            float* __restrict__ GWP) {
    const int t = blockIdx.z & 3, kh = blockIdx.z >> 2;
    const __bf16* A  = AB  + (size_t)t * 2048 + (size_t)kh * 1024;
    const __bf16* BT = WTT + (size_t)t * 384 * 2048 + (size_t)kh * 1024;
    float* C = GWP + (size_t)blockIdx.z * NN * 384;
    mfma_core<0, 0>(A, 8192, BT, 2048, C, 384, nullptr, NN, 1024,
                    blockIdx.y * 128, blockIdx.x * 128);
}

// H = OB @ lin_w + lin_b (K=512, N=512) -> fp32
__global__ __launch_bounds__(256) void k_lin(const __bf16* __restrict__ OB, const __bf16* __restrict__ WLINT,
                                             const float* __restrict__ bl, float* __restrict__ H) {
    mfma_core<0, 1>(OB, 512, WLINT, 512, H, 512, bl, NN, 512,
                    blockIdx.y * 128, blockIdx.x * 128);
}

// =============== fused weight transpose/convert fp32 -> bf16 (one launch) ===============
__device__ __forceinline__ void tr32(const float* __restrict__ S, int sld,
                                     __bf16* __restrict__ D, int dld) {
    __shared__ float t[32][33];
    const int x = threadIdx.x, y0 = threadIdx.y * 4;
#pragma unroll
    for (int i = 0; i < 4; ++i) t[y0 + i][x] = S[(size_t)(y0 + i) * sld + x];
    __syncthreads();
#pragma unroll
    for (int i = 0; i < 4; ++i) D[(size_t)(y0 + i) * dld + x] = (__bf16)t[x][y0 + i];
}

// jobs: [0,2048) pre Wi/Wj -> WCAT rows 0..4095; [2048,2304) W0 -> WCAT rows 4096..4607;
//       [2304,5376) WTT; [5376,5632) WLINT
__global__ void k_tr(const float* __restrict__ pw, const float* __restrict__ pow_,
                     const float* __restrict__ lw,
                     __bf16* __restrict__ WCAT, __bf16* __restrict__ WTT, __bf16* __restrict__ WLINT) {
    int id = blockIdx.x;
    if (id < 2048) {
        const int z = id >> 8, r = id & 255;
        const int t = z & 3, half = z >> 2;
        const int x = r & 15, y = r >> 4;
        const float* S = pw + ((size_t)(t * 1536 + half * 512 + y * 32)) * 512 + x * 32;
        __bf16* D = WCAT + ((size_t)(half * 2048 + t * 512 + x * 32)) * 512 + y * 32;
        tr32(S, 512, D, 512);
    } else if (id < 2304) {
        const int id3 = id - 2048;
        const int t = id3 >> 6, r = id3 & 63;
        const int x = r & 3, y = r >> 2;
        const float* S = pow_ + ((size_t)(t * 6656 + y * 32)) * 128 + x * 32;
        __bf16* D = WCAT + ((size_t)(4096 + t * 128 + x * 32)) * 512 + y * 32;
        tr32(S, 128, D, 512);
    } else if (id < 5376) {
        const int id4 = id - 2304;
        const int z = id4 >> 8, r = id4 & 255;
        const int t = z / 3, w = z % 3;
        const int x = r & 3, y = r >> 2;
        const float* S = pow_ + ((size_t)(t * 6656 + 512 + w * 2048 + y * 32)) * 128 + x * 32;
        __bf16* D = WTT + (size_t)t * 384 * 2048 + ((size_t)(w * 128 + x * 32)) * 2048 + y * 32;
        tr32(S, 128, D, 2048);
    } else {
        const int r = id - 5376;
        const int x = r & 15, y = r >> 4;
        const float* S = lw + (size_t)y * 32 * 512 + x * 32;
        __bf16* D = WLINT + (size_t)x * 32 * 512 + y * 32;
        tr32(S, 512, D, 512);
    }
}

// ---------------- graph prep ----------------
__global__ void k_count(const int* __restrict__ dst, int* __restrict__ cnt) {
    int e = blockIdx.x * 256 + threadIdx.x;
    if (e < NE) atomicAdd(&cnt[dst[e]], 1);
}

__global__ __launch_bounds__(1024) void k_scan(const int* __restrict__ cnt, int* __restrict__ offs,
                                               float* __restrict__ amp, float* __restrict__ ramp) {
    __shared__ int part[1024];
    const int t = threadIdx.x;
    const int base = t * 4;
    int loc[4]; int s = 0;
#pragma unroll
    for (int i = 0; i < 4; ++i) { int v = (base + i < NN) ? cnt[base + i] : 0; loc[i] = s; s += v; }
    part[t] = s;
    __syncthreads();
    for (int o = 1; o < 1024; o <<= 1) {
        int v = (t >= o) ? part[t - o] : 0;
        __syncthreads();
        part[t] += v;
        __syncthreads();
    }
    const int pre = (t > 0) ? part[t - 1] : 0;
#pragma unroll
    for (int i = 0; i < 4; ++i) if (base + i < NN) offs[base + i] = pre + loc[i];
    if (t == 1023) offs[NN] = part[1023];
    for (int n = t; n < NN; n += 1024) {
        float deg = fmaxf((float)cnt[n], 1.0f);
        float a = logf(deg + 1.0f) / AVGLOG;
        amp[n] = a; ramp[n] = 1.0f / a;
    }
}

__global__ void k_fill(const int* __restrict__ src, const int* __restrict__ dst,
                       const int* __restrict__ sgn, const int* __restrict__ offs,
                       int* __restrict__ fill, int* __restrict__ esrc, int* __restrict__ esgn) {
    int e = blockIdx.x * 256 + threadIdx.x;
    if (e < NE) {
        int d = dst[e];
        int pos = offs[d] + atomicAdd(&fill[d], 1);
        esrc[pos] = src[e];
        esgn[pos] = sgn[e];
    }
}

// ---------------- node features ----------------
__global__ void k_build_x(const float* __restrict__ nemb, const float* __restrict__ acts,
                          const float* __restrict__ pew, const float* __restrict__ peb,
                          const int* __restrict__ gidx, float* __restrict__ X, __bf16* __restrict__ XB) {
    int idx = blockIdx.x * 256 + threadIdx.x;
    int n = idx >> 9, d = idx & 511;
    float v = nemb[(size_t)gidx[n] * DD + d] + acts[n * 2] * pew[d] + acts[n * 2 + 1] * pew[DD + d] + peb[d];
    X[idx] = v; XB[idx] = (__bf16)v;
}

// fused: EK (LDS) then EM[k][t*512+d] = ek[k] @ We_fp32 + pre_b
__global__ __launch_bounds__(256) void k_ekem(const float* __restrict__ eemb, const float* __restrict__ eew,
                                              const float* __restrict__ eeb, const float* __restrict__ pw,
                                              const float* __restrict__ pb, float* __restrict__ EM) {
    __shared__ float EKs[1024];
    const int tid = threadIdx.x;
    for (int i = tid; i < 1024; i += 256) {
        int k = i >> 9, d = i & 511;
        float s = eeb[d];
        for (int f = 0; f < 50; ++f) s += eemb[k * 50 + f] * eew[(size_t)f * 512 + d];
        EKs[i] = s;
    }
    __syncthreads();
    const int idx = blockIdx.x * 256 + tid;  // 0..4095
    const int k = idx >> 11, g = idx & 2047;
    const int t = g >> 9, d = g & 511;
    const float* ek = EKs + k * 512;
    const float* W = pw + ((size_t)t * 1536 + 1024) * 512 + d;   // We fp32, stride 512
    float s = pb[g];
    for (int f = 0; f < 512; ++f) s += ek[f] * W[(size_t)f * 512];
    EM[idx] = s;
}

// ---------------- aggregation: one block per dst node ----------------
__global__ __launch_bounds__(256) void k_agg(const __bf16* __restrict__ XG, const float* __restrict__ EM,
                                             const int* __restrict__ offs, const int* __restrict__ cnt,
                                             const int* __restrict__ esrc, const int* __restrict__ esgn,
                                             __bf16* __restrict__ AB) {
    const int n = blockIdx.x;
    const int g = threadIdx.x * 8;  // (t,d) flat, 8 contiguous d
    float xid[8], em0[8], em1[8];
    {
        bf16x8 xb = *(const bf16x8*)(XG + (size_t)n * XGW + g);
#pragma unroll
        for (int i = 0; i < 8; ++i) xid[i] = (float)xb[i];
    }
    *(float4*)&em0[0] = *(const float4*)&EM[g];
    *(float4*)&em0[4] = *(const float4*)&EM[g + 4];
    *(float4*)&em1[0] = *(const float4*)&EM[2048 + g];
    *(float4*)&em1[4] = *(const float4*)&EM[2048 + g + 4];
    float s1[8], s2[8], mn[8], mx[8];
#pragma unroll
    for (int i = 0; i < 8; ++i) { s1[i] = 0.f; s2[i] = 0.f; mn[i] = FLT_MAX; mx[i] = -FLT_MAX; }
    const int j0 = offs[n], j1 = offs[n + 1];
    for (int j = j0; j < j1; ++j) {
        const int s = esrc[j];
        const int sg = esgn[j];
        bf16x8 xv = *(const bf16x8*)(XG + (size_t)s * XGW + 2048 + g);
#pragma unroll
        for (int i = 0; i < 8; ++i) {
            float m = xid[i] + (float)xv[i] + (sg ? em1[i] : em0[i]);
            s1[i] += m; s2[i] += m * m;
            mn[i] = fminf(mn[i], m); mx[i] = fmaxf(mx[i], m);
        }
    }
    const int c = cnt[n];
    const float deg = fmaxf((float)c, 1.0f);
    const float rdeg = 1.0f / deg;
    bf16x8 vmean, vmn, vmx, vsd;
#pragma unroll
    for (int i = 0; i < 8; ++i) {
        float mean = s1[i] * rdeg;
        float var = s2[i] * rdeg - mean * mean;
        float sd = sqrtf(fmaxf(var, 0.f) + EPS_STD_);
        float mnv = (c == 0) ? 0.f : mn[i];
        float mxv = (c == 0) ? 0.f : mx[i];
        vmean[i] = (__bf16)mean; vmn[i] = (__bf16)mnv; vmx[i] = (__bf16)mxv; vsd[i] = (__bf16)sd;
    }
    const int t = g >> 9, d = g & 511;
    __bf16* base = AB + (size_t)n * 8192 + (size_t)t * 2048 + d;
    *(bf16x8*)(base + 0 * DD) = vmean;
    *(bf16x8*)(base + 1 * DD) = vmn;
    *(bf16x8*)(base + 2 * DD) = vmx;
    *(bf16x8*)(base + 3 * DD) = vsd;
}

// O[n][t*128+o] = GX + (GWa+GWb) with amp weighting + post_b -> bf16
__global__ void k_combine(const __bf16* __restrict__ XG, const float* __restrict__ GWP,
                          const float* __restrict__ amp, const float* __restrict__ ramp,
                          const float* __restrict__ pb, __bf16* __restrict__ OB) {
    int idx = blockIdx.x * 256 + threadIdx.x;
    int n = idx >> 9, c = idx & 511;
    int t = c >> 7, o = c & 127;
    const float* ga = GWP + ((size_t)t) * NN * 384 + (size_t)n * 384;
    const float* gb = GWP + ((size_t)(4 + t)) * NN * 384 + (size_t)n * 384;
    float w1 = ga[o] + gb[o];
    float w2 = ga[128 + o] + gb[128 + o];
    float w3 = ga[256 + o] + gb[256 + o];
    float gx = (float)XG[(size_t)n * XGW + 4096 + c];
    float v = gx + w1 + amp[n] * w2 + ramp[n] * w3 + pb[c];
    OB[idx] = (__bf16)v;
}

// ---------------- batchnorm ----------------
__global__ void k_bnstat(const float* __restrict__ H, float* __restrict__ BN) {
    int cidx = blockIdx.x * 256 + threadIdx.x;  // column 0..511
    int r0 = blockIdx.y * 125;
    float s = 0.f, q = 0.f;
    for (int r = r0; r < r0 + 125; ++r) { float v = H[(size_t)r * DD + cidx]; s += v; q += v * v; }
    atomicAdd(&BN[cidx], s); atomicAdd(&BN[DD + cidx], q);
}

__global__ void k_bnapply(const float* __restrict__ H, const float* __restrict__ BN,
                          const float* __restrict__ gamma, const float* __restrict__ beta,
                          float* __restrict__ X, __bf16* __restrict__ XB) {
    int idx = blockIdx.x * 256 + threadIdx.x;
    int d = idx & 511;
    float mu = BN[d] * (1.0f / NN);
    float var = BN[DD + d] * (1.0f / NN) - mu * mu;
    float v = gamma[d] * (H[idx] - mu) * rsqrtf(var + EPS_BN_) + beta[d];
    v = fmaxf(v, 0.f);
    X[idx] = v; XB[idx] = (__bf16)v;
}

// ---------------- readout ----------------
__global__ void k_pool(const float* __restrict__ X, const int* __restrict__ batch, float* __restrict__ PL) {
    int idx = blockIdx.x * 256 + threadIdx.x;
    int n = idx >> 9, d = idx & 511;
    atomicAdd(&PL[(size_t)batch[n] * DD + d], X[idx]);
}

__global__ void k_fc1(const float* __restrict__ PL, const float* __restrict__ W1,
                      const float* __restrict__ b1, const float* __restrict__ pa, float* __restrict__ Z) {
    int idx = blockIdx.x * 256 + threadIdx.x;  // 0..32767
    int g = idx >> 10, j = idx & 1023;
    float s = b1[j];
    const float* p = PL + (size_t)g * DD;
    for (int f = 0; f < DD; ++f) s += p[f] * W1[(size_t)f * 1024 + j];
    float a = *pa;
    Z[idx] = s > 0.f ? s : a * s;
}

__global__ __launch_bounds__(64) void k_out(const float* __restrict__ Z, const float* __restrict__ Wo,
                                            const float* __restrict__ bo, float* __restrict__ out) {
    int g = blockIdx.x, t = threadIdx.x;
    float part[NC];
#pragma unroll
    for (int c = 0; c < NC; ++c) part[c] = 0.f;
    for (int f = t; f < 1024; f += 64) {
        float zv = Z[g * 1024 + f];
#pragma unroll
        for (int c = 0; c < NC; ++c) part[c] += zv * Wo[(size_t)f * NC + c];
    }
#pragma unroll
    for (int off = 32; off > 0; off >>= 1)
#pragma unroll
        for (int c = 0; c < NC; ++c) part[c] += __shfl_down(part[c], off);
    if (t == 0) {
        float lg[NC], mxv = -FLT_MAX;
#pragma unroll
        for (int c = 0; c < NC; ++c) { lg[c] = part[c] + bo[c]; mxv = fmaxf(mxv, lg[c]); }
        float se = 0.f;
#pragma unroll
        for (int c = 0; c < NC; ++c) se += expf(lg[c] - mxv);
        float lse = mxv + logf(se);
#pragma unroll
        for (int c = 0; c < NC; ++c) out[g * NC + c] = lg[c] - lse;
    }
}

extern "C" void kernel_launch(void* const* d_in, const int* in_sizes, int n_in,
                              void* d_out, int out_size, void* d_ws, size_t ws_size,
                              hipStream_t stream) {
    const float* node_emb_w = (const float*)d_in[0];
    const float* edge_emb_w = (const float*)d_in[1];
    const float* pe_w   = (const float*)d_in[2];
    const float* pe_b   = (const float*)d_in[3];
    const float* edge_enc_w = (const float*)d_in[4];
    const float* edge_enc_b = (const float*)d_in[5];
    const float* pre_w  = (const float*)d_in[6];
    const float* pre_b  = (const float*)d_in[7];
    const float* post_w = (const float*)d_in[8];
    const float* post_b = (const float*)d_in[9];
    const float* lin_w  = (const float*)d_in[10];
    const float* lin_b  = (const float*)d_in[11];
    const float* bn_gamma = (const float*)d_in[12];
    const float* bn_beta  = (const float*)d_in[13];
    const float* acts   = (const float*)d_in[14];
    const float* fc1_w  = (const float*)d_in[15];
    const float* fc1_b  = (const float*)d_in[16];
    const float* fc_out_w = (const float*)d_in[17];
    const float* fc_out_b = (const float*)d_in[18];
    const float* prelu_a  = (const float*)d_in[19];
    const int* global_idx = (const int*)d_in[20];
    const int* sgn        = (const int*)d_in[21];
    const int* edge_index = (const int*)d_in[22];
    const int* batch      = (const int*)d_in[23];
    float* out = (float*)d_out;

    char* W = (char*)d_ws;
    size_t off = 0;
    auto alloc = [&](size_t bytes) { void* p = W + off; off += (bytes + 63) & ~(size_t)63; return p; };
    float*  X     = (float*)alloc((size_t)NN * DD * 4);
    __bf16* XB    = (__bf16*)alloc((size_t)NN * DD * 2);
    float*  H     = (float*)alloc((size_t)NN * DD * 4);
    __bf16* XG    = (__bf16*)alloc((size_t)NN * XGW * 2);
    __bf16* AB    = (__bf16*)alloc((size_t)NN * 8192 * 2);
    float*  GWP   = (float*)alloc((size_t)8 * NN * 384 * 4);
    __bf16* OB    = (__bf16*)alloc((size_t)NN * DD * 2);
    __bf16* WCAT  = (__bf16*)alloc((size_t)XGW * 512 * 2);
    __bf16* WTT   = (__bf16*)alloc((size_t)NT * 384 * 2048 * 2);
    __bf16* WLINT = (__bf16*)alloc((size_t)512 * 512 * 2);
    float*  EM    = (float*)alloc(2 * 2048 * 4);
    float*  BN    = (float*)alloc(2 * 512 * 4);
    float*  PL    = (float*)alloc((size_t)NG * DD * 4);
    float*  ZB    = (float*)alloc((size_t)NG * 1024 * 4);
    float*  AMP   = (float*)alloc(NN * 4);
    float*  RAMP  = (float*)alloc(NN * 4);
    int*    CNT   = (int*)alloc(NN * 4);
    int*    OFFS  = (int*)alloc((NN + 1) * 4);
    int*    FILL  = (int*)alloc(NN * 4);
    int*    ESRC  = (int*)alloc(NE * 4);
    int*    ESGN  = (int*)alloc(NE * 4);

    const int* src = edge_index;
    const int* dst = edge_index + NE;

    hipMemsetAsync(CNT, 0, NN * sizeof(int), stream);
    hipMemsetAsync(FILL, 0, NN * sizeof(int), stream);
    k_count<<<(NE + 255) / 256, 256, 0, stream>>>(dst, CNT);
    k_scan<<<1, 1024, 0, stream>>>(CNT, OFFS, AMP, RAMP);
    k_fill<<<(NE + 255) / 256, 256, 0, stream>>>(src, dst, sgn, OFFS, FILL, ESRC, ESGN);
    k_build_x<<<NN * DD / 256, 256, 0, stream>>>(node_emb_w, acts, pe_w, pe_b, global_idx, X, XB);

    for (int l = 0; l < 2; ++l) {
        const float* pre_w_l  = pre_w  + (size_t)l * NT * 3 * DD * DD;
        const float* pre_b_l  = pre_b  + (size_t)l * NT * DD;
        const float* post_w_l = post_w + (size_t)l * NT * 6656 * FO;
        const float* post_b_l = post_b + (size_t)l * NT * FO;
        const float* lin_w_l  = lin_w  + (size_t)l * DD * DD;
        const float* lin_b_l  = lin_b  + (size_t)l * DD;
        const float* eew_l    = edge_enc_w + (size_t)l * 50 * DD;
        const float* eeb_l    = edge_enc_b + (size_t)l * DD;

        k_tr<<<5632, dim3(32, 8), 0, stream>>>(pre_w_l, post_w_l, lin_w_l, WCAT, WTT, WLINT);
        k_ekem<<<16, 256, 0, stream>>>(edge_emb_w, eew_l, eeb_l, pre_w_l, pre_b_l, EM);

        // XG = X @ [Wi|Wj|W0]^T  (M=4000, K=512, N=4608) -> bf16
        k_xg<<<dim3(36, 32), 256, 0, stream>>>(XB, WCAT, XG);
        k_agg<<<NN, 256, 0, stream>>>(XG, EM, OFFS, CNT, ESRC, ESGN, AB);
        // GWP = split-K x2 batched tower GEMM (M=4000, K=1024, N=384) x 8
        k_gw<<<dim3(3, 32, 8), 256, 0, stream>>>(AB, WTT, GWP);
        k_combine<<<NN * DD / 256, 256, 0, stream>>>(XG, GWP, AMP, RAMP, post_b_l, OB);
        // H = O @ lin_w + lin_b
        k_lin<<<dim3(4, 32), 256, 0, stream>>>(OB, WLINT, lin_b_l, H);

        hipMemsetAsync(BN, 0, 2 * DD * sizeof(float), stream);
        k_bnstat<<<dim3(2, 32), 256, 0, stream>>>(H, BN);
        k_bnapply<<<NN * DD / 256, 256, 0, stream>>>(H, BN, bn_gamma + (size_t)l * DD, bn_beta + (size_t)l * DD, X, XB);
    }

    hipMemsetAsync(PL, 0, NG * DD * sizeof(float), stream);
    k_pool<<<NN * DD / 256, 256, 0, stream>>>(X, batch, PL);
    k_fc1<<<NG * 1024 / 256, 256, 0, stream>>>(PL, fc1_w, fc1_b, prelu_a, ZB);
    k_out<<<NG, 64, 0, stream>>>(ZB, fc_out_w, fc_out_b, out);
}